// Round 1
// baseline (221.165 us; speedup 1.0000x reference)
//
#include <hip/hip_runtime.h>

// Problem constants (from reference): N=65536, D_OUT=128, D_LAT=64, D_Z=64
constexpr int N_ROWS  = 65536;
constexpr int BLOCKS  = 512;
constexpr int THREADS = 256;
constexpr int T_TOT   = BLOCKS * THREADS;   // 131072, divisible by 16

// ws layout (floats): [0]=recon_sum, [1]=kl_sum,
// [2+0*64 + j] = sum z_t[:,j]
// [2+1*64 + j] = sum z_tau[:,j]
// [2+2*64 + j] = sum z_t[:,j]^2
// [2+3*64 + j] = sum z_tau[:,j]^2
// [2+4*64 + j] = sum z_t[:,j]*z_tau[:,j]
// total 322 floats

__global__ __launch_bounds__(THREADS) void vde_reduce(
    const float4* __restrict__ target,
    const float4* __restrict__ output,
    const float4* __restrict__ mean,
    const float4* __restrict__ logvar,
    const float4* __restrict__ zt,
    const float4* __restrict__ ztau,
    float* __restrict__ ws)
{
    const int tid = blockIdx.x * THREADS + threadIdx.x;

    // ---- reconstruction MSE partial: sum (o - t)^2 ----
    float recon = 0.f;
    constexpr int R4 = N_ROWS * 128 / 4;    // 2097152 float4s, 16 iters/thread
    #pragma unroll 4
    for (int f = tid; f < R4; f += T_TOT) {
        float4 o = output[f];
        float4 t = target[f];
        float dx = o.x - t.x, dy = o.y - t.y, dz = o.z - t.z, dw = o.w - t.w;
        recon += dx * dx + dy * dy + dz * dz + dw * dw;
    }

    // ---- KL partial: sum (lv - e^lv - m^2 + 1) ----
    float kls = 0.f;
    constexpr int K4 = N_ROWS * 64 / 4;     // 1048576 float4s, 8 iters/thread
    #pragma unroll 4
    for (int f = tid; f < K4; f += T_TOT) {
        float4 lv = logvar[f];
        float4 m  = mean[f];
        kls += (lv.x - __expf(lv.x) - m.x * m.x + 1.f)
             + (lv.y - __expf(lv.y) - m.y * m.y + 1.f)
             + (lv.z - __expf(lv.z) - m.z * m.z + 1.f)
             + (lv.w - __expf(lv.w) - m.w * m.w + 1.f);
    }

    // ---- per-column z statistics ----
    // float4 index f has f % 16 == tid % 16 (T_TOT % 16 == 0), so each thread
    // covers the fixed 4-column group g = tid & 15 -> columns 4g..4g+3.
    float s_t[4]  = {0, 0, 0, 0}, s_t2[4] = {0, 0, 0, 0};
    float s_a[4]  = {0, 0, 0, 0}, s_a2[4] = {0, 0, 0, 0};
    float s_c[4]  = {0, 0, 0, 0};
    constexpr int Z4 = N_ROWS * 64 / 4;     // 8 iters/thread
    #pragma unroll 4
    for (int f = tid; f < Z4; f += T_TOT) {
        float4 a = zt[f];
        float4 b = ztau[f];
        s_t[0] += a.x; s_t2[0] += a.x * a.x; s_a[0] += b.x; s_a2[0] += b.x * b.x; s_c[0] += a.x * b.x;
        s_t[1] += a.y; s_t2[1] += a.y * a.y; s_a[1] += b.y; s_a2[1] += b.y * b.y; s_c[1] += a.y * b.y;
        s_t[2] += a.z; s_t2[2] += a.z * a.z; s_a[2] += b.z; s_a2[2] += b.z * b.z; s_c[2] += a.z * b.z;
        s_t[3] += a.w; s_t2[3] += a.w * a.w; s_a[3] += b.w; s_a2[3] += b.w * b.w; s_c[3] += a.w * b.w;
    }

    // ---- scalar wave reduction (64 lanes) ----
    #pragma unroll
    for (int m = 32; m >= 1; m >>= 1) {
        recon += __shfl_xor(recon, m);
        kls   += __shfl_xor(kls, m);
    }
    const int lane = threadIdx.x & 63;
    if (lane == 0) {
        atomicAdd(&ws[0], recon);
        atomicAdd(&ws[1], kls);
    }

    // ---- per-column-group reduction: lanes {l, l^16, l^32, l^48} share group ----
    float vals[20];
    #pragma unroll
    for (int e = 0; e < 4; ++e) {
        vals[e * 5 + 0] = s_t[e];
        vals[e * 5 + 1] = s_a[e];
        vals[e * 5 + 2] = s_t2[e];
        vals[e * 5 + 3] = s_a2[e];
        vals[e * 5 + 4] = s_c[e];
    }
    #pragma unroll
    for (int v = 0; v < 20; ++v) {
        vals[v] += __shfl_xor(vals[v], 16);
        vals[v] += __shfl_xor(vals[v], 32);
    }

    __shared__ float sred[4][16][20];
    const int wave = threadIdx.x >> 6;      // 0..3
    if (lane < 16) {
        #pragma unroll
        for (int v = 0; v < 20; ++v) sred[wave][lane][v] = vals[v];
    }
    __syncthreads();

    // 16 groups * 20 values = 320 partials -> global atomics (one per block each)
    for (int i = threadIdx.x; i < 320; i += THREADS) {
        const int g = i / 20, v = i % 20;
        const float s = sred[0][g][v] + sred[1][g][v] + sred[2][g][v] + sred[3][g][v];
        const int e = v / 5, st = v % 5;
        const int col = g * 4 + e;
        atomicAdd(&ws[2 + st * 64 + col], s);
    }
}

__global__ __launch_bounds__(64) void vde_finalize(
    const float* __restrict__ ws, float* __restrict__ out)
{
    const int j = threadIdx.x;              // column 0..63
    const float Nf = (float)N_ROWS;

    const float sum_t   = ws[2 + 0 * 64 + j];
    const float sum_a   = ws[2 + 1 * 64 + j];
    const float sum_t2  = ws[2 + 2 * 64 + j];
    const float sum_a2  = ws[2 + 3 * 64 + j];
    const float sum_c   = ws[2 + 4 * 64 + j];

    const float mu_t  = sum_t / Nf;
    const float mu_a  = sum_a / Nf;
    float diag = sum_c - Nf * mu_t * mu_a;                 // sum_i centered cross
    const float var_t = (sum_t2 - Nf * mu_t * mu_t) / (Nf - 1.f);
    const float var_a = (sum_a2 - Nf * mu_a * mu_a) / (Nf - 1.f);
    float sp = sqrtf(var_t) * sqrtf(var_a);                // std_t[j]*std_tau[j]

    #pragma unroll
    for (int m = 32; m >= 1; m >>= 1) {
        diag += __shfl_xor(diag, m);
        sp   += __shfl_xor(sp, m);
    }

    if (j == 0) {
        const float recon  = ws[0] / (Nf * 128.f);
        const float kl     = -0.5f * ws[1] / Nf;
        const float auto_l = -(diag / Nf) / sp;
        out[0] = recon + kl + auto_l;
    }
}

extern "C" void kernel_launch(void* const* d_in, const int* in_sizes, int n_in,
                              void* d_out, int out_size, void* d_ws, size_t ws_size,
                              hipStream_t stream) {
    const float4* target = (const float4*)d_in[0];
    const float4* output = (const float4*)d_in[1];
    const float4* mean   = (const float4*)d_in[2];
    const float4* logvar = (const float4*)d_in[3];
    const float4* zt     = (const float4*)d_in[4];
    const float4* ztau   = (const float4*)d_in[5];
    float* ws  = (float*)d_ws;
    float* out = (float*)d_out;

    // ws is re-poisoned to 0xAA before every timed launch -> zero the accumulators
    hipMemsetAsync(ws, 0, 322 * sizeof(float), stream);
    vde_reduce<<<BLOCKS, THREADS, 0, stream>>>(target, output, mean, logvar, zt, ztau, ws);
    vde_finalize<<<1, 64, 0, stream>>>(ws, out);
}